// Round 1
// baseline (434.400 us; speedup 1.0000x reference)
//
#include <hip/hip_runtime.h>

typedef _Float16 f16;
typedef _Float16 f16x8 __attribute__((ext_vector_type(8)));
typedef float f32x4 __attribute__((ext_vector_type(4)));

#define LN4 1.3862943611198906f

__device__ __forceinline__ void gl_lds16(const void* g, void* l) {
    typedef unsigned int u32;
    __builtin_amdgcn_global_load_lds(
        (const __attribute__((address_space(1))) u32*)(g),
        (__attribute__((address_space(3))) u32*)(l), 16, 0, 0);
}

__device__ __forceinline__ float bcast_lane(float v, int srclane) {
    return __uint_as_float(__builtin_amdgcn_readlane(__float_as_uint(v), srclane));
}

// ===========================================================================
// Level-1 weight prep: fp32 W1[27][80][80] -> f16 hi/lo transposed:
// WT[d][tap][ h(80) | l(80) ], d<80, tap<28 (tap 27 = zeros).
// ===========================================================================
__global__ __launch_bounds__(256) void prep_w1_kernel(
    const float* __restrict__ W, f16* __restrict__ dst)
{
    const int CIN = 80, COUT = 80;
    int total = COUT * 28 * CIN;
    for (int i = blockIdx.x * 256 + threadIdx.x; i < total; i += gridDim.x * 256) {
        int d = i / (28 * CIN);
        int rem = i - d * (28 * CIN);
        int tap = rem / CIN;
        int c = rem - tap * CIN;
        float v = (tap < 27) ? W[(size_t)(tap * CIN + c) * COUT + d] : 0.f;
        f16 h = (f16)v;
        size_t base = (size_t)d * (28 * 2 * CIN) + (size_t)tap * (2 * CIN);
        dst[base + c] = h;
        dst[base + CIN + c] = (f16)(v - (float)h);
    }
}

// Level-1 feature split: rows [h(80)|l(80)] f16, zero-sentinel row at n==N.
__global__ __launch_bounds__(256) void split80_kernel(
    const float* __restrict__ f, f16* __restrict__ Fc, int N)
{
    int i = blockIdx.x * 256 + threadIdx.x;
    if (i >= (N + 1) * 80) return;
    int n = i / 80, c = i - n * 80;
    float v = (n < N) ? f[i] : 0.f;
    f16 h = (f16)v;
    Fc[(size_t)n * 160 + c] = h;
    Fc[(size_t)n * 160 + 80 + c] = (f16)(v - (float)h);
}

__global__ __launch_bounds__(256) void ppn_finalize_kernel(
    const int* __restrict__ coords, const float* __restrict__ s,
    float* __restrict__ ppn, float* __restrict__ mask, int N)
{
    int n = blockIdx.x * 256 + threadIdx.x;
    if (n >= N) return;
    float s0 = s[(size_t)n * 2 + 0], s1 = s[(size_t)n * 2 + 1];
    ppn[(size_t)n * 6 + 0] = (float)coords[(size_t)n * 4 + 0];
    ppn[(size_t)n * 6 + 1] = (float)coords[(size_t)n * 4 + 1];
    ppn[(size_t)n * 6 + 2] = (float)coords[(size_t)n * 4 + 2];
    ppn[(size_t)n * 6 + 3] = (float)coords[(size_t)n * 4 + 3];
    ppn[(size_t)n * 6 + 4] = s0;
    ppn[(size_t)n * 6 + 5] = s1;
    mask[n] = (s1 - s0 > LN4) ? 1.0f : 0.0f;
}

// act[i] = mask[parent[i]]
__global__ __launch_bounds__(256) void gate_kernel(
    const float* __restrict__ mask, const int* __restrict__ parent,
    float* __restrict__ act, int N)
{
    int i = blockIdx.x * 256 + threadIdx.x;
    if (i < N) act[i] = mask[parent[i]];
}

// flag[nbr[m][t]] = 1 for every active source m (nbr symmetry => exact
// "row n has >=1 active neighbor" indicator). FSRC: float src, else int src.
template<bool FSRC>
__global__ __launch_bounds__(256) void expand_kernel(
    const void* __restrict__ src, const int* __restrict__ nbr,
    int* __restrict__ flag, int N)
{
    int m = blockIdx.x * 256 + threadIdx.x;
    if (m >= N) return;
    bool a = FSRC ? (((const float*)src)[m] != 0.f) : (((const int*)src)[m] != 0);
    if (!a) return;
    #pragma unroll 1
    for (int t = 0; t < 27; ++t) {
        int idx = nbr[(size_t)m * 27 + t];
        if (idx < N) flag[idx] = 1;
    }
}

// wave-aggregated compaction: list[0..cnt) = rows with flag!=0
__global__ __launch_bounds__(256) void compact_kernel(
    const int* __restrict__ flag, int* __restrict__ list,
    int* __restrict__ cnt, int N)
{
    int i = blockIdx.x * 256 + threadIdx.x;
    int lane = threadIdx.x & 63;
    bool f = (i < N) && (flag[i] != 0);
    unsigned long long m = __ballot(f);
    int base = 0;
    if (lane == 0 && m) base = atomicAdd(cnt, __popcll(m));
    base = __shfl(base, 0);
    if (f) list[base + __popcll(m & ((1ull << lane) - 1ull))] = i;
}

// ===========================================================================
// Level 1: MFMA conv80 (f16-split, 3-term) fused with scatter score conv.
// (R5-measured structure, unchanged.)
// ===========================================================================
__global__ __launch_bounds__(256, 3) void conv80_scat(
    const f16* __restrict__ F, const int* __restrict__ nbr,
    const f16* __restrict__ WT, const float* __restrict__ Wsc,
    float* __restrict__ sout, int N, int nTiles)
{
    constexpr int RE = 160, CPT = 20, CPR = 40, PB = 640, KB = 5, BM = 64;
    __shared__ __align__(16) char BS[80 * PB];     // 51200 B

    const int t = threadIdx.x;
    const int lane = t & 63;
    const int l16 = lane & 15;
    const int quad = lane >> 4;
    const int wv = t >> 6;

    int q8 = (nTiles + 7) >> 3;
    int tile = (blockIdx.x & 7) * q8 + (blockIdx.x >> 3);
    if (tile >= nTiles) return;
    const int m0 = tile * BM;
    const int grow = m0 + wv * 16 + l16;

    f16x8 ah[2][KB], al[2][KB];

    auto loadA = [&](int p, int buf) {
        int i0 = N, i1 = N;
        if (grow < N) {
            i0 = nbr[(size_t)grow * 27 + 2 * p];
            if (2 * p + 1 < 27) i1 = nbr[(size_t)grow * 27 + 2 * p + 1];
        }
        #pragma unroll
        for (int kb = 0; kb < KB; ++kb) {
            int ko = kb * 32 + quad * 8;
            int ts = ko >= 80;
            int c2 = ko - (ts ? 80 : 0);
            const f16* ap = F + (size_t)(ts ? i1 : i0) * RE + c2;
            ah[buf][kb] = *(const f16x8*)ap;
            al[buf][kb] = *(const f16x8*)(ap + 80);
        }
    };

    auto stageB = [&](int p) {
        for (int i = t; i < 80 * CPR; i += 256) {
            int d = i / CPR, cs = i - d * CPR;
            int c = (cs & ~7) | ((cs ^ d) & 7);
            int tp = c / CPT, cc = c - tp * CPT;
            gl_lds16((const char*)WT + (((size_t)d * 28 + 2 * p + tp) * RE + cc * 8) * 2,
                     BS + (size_t)i * 16);
        }
    };

    f32x4 acc[5];
    #pragma unroll
    for (int ct = 0; ct < 5; ++ct) acc[ct] = (f32x4){0.f, 0.f, 0.f, 0.f};

    auto compute = [&](int buf) {
        #pragma unroll
        for (int kb = 0; kb < KB; ++kb) {
            int ko = kb * 32 + quad * 8;
            int ts = ko >= 80;
            int c2 = ko - (ts ? 80 : 0);
            int ch = ts * CPT + c2 / 8;
            int chl = ch + 10;
            #pragma unroll
            for (int ct = 0; ct < 5; ++ct) {
                int drow = ct * 16 + l16;
                int sb = (ch & ~7) | ((ch ^ drow) & 7);
                int sbl = (chl & ~7) | ((chl ^ drow) & 7);
                f16x8 bh = *(const f16x8*)(BS + drow * PB + sb * 16);
                f16x8 bl = *(const f16x8*)(BS + drow * PB + sbl * 16);
                acc[ct] = __builtin_amdgcn_mfma_f32_16x16x32_f16(ah[buf][kb], bh, acc[ct], 0, 0, 0);
                acc[ct] = __builtin_amdgcn_mfma_f32_16x16x32_f16(al[buf][kb], bh, acc[ct], 0, 0, 0);
                acc[ct] = __builtin_amdgcn_mfma_f32_16x16x32_f16(ah[buf][kb], bl, acc[ct], 0, 0, 0);
            }
        }
    };

    loadA(0, 0);
    #pragma unroll 1
    for (int p = 0; p < 14; ++p) {
        __syncthreads();
        stageB(p);
        if (p < 13) loadA(p + 1, (p + 1) & 1);
        __syncthreads();
        compute(p & 1);
    }

    #pragma unroll 1
    for (int tap = 0; tap < 27; ++tap) {
        float q0[4] = {}, q1[4] = {};
        #pragma unroll
        for (int ct = 0; ct < 5; ++ct) {
            float2 w = ((const float2*)Wsc)[(size_t)(26 - tap) * 80 + ct * 16 + l16];
            #pragma unroll
            for (int r = 0; r < 4; ++r) { q0[r] += acc[ct][r] * w.x; q1[r] += acc[ct][r] * w.y; }
        }
        #pragma unroll
        for (int m = 1; m < 16; m <<= 1) {
            #pragma unroll
            for (int r = 0; r < 4; ++r) { q0[r] += __shfl_xor(q0[r], m); q1[r] += __shfl_xor(q1[r], m); }
        }
        if (l16 < 8) {
            int r = l16 >> 1, j = l16 & 1;
            float v0 = (r == 0) ? q0[0] : (r == 1) ? q0[1] : (r == 2) ? q0[2] : q0[3];
            float v1 = (r == 0) ? q1[0] : (r == 1) ? q1[1] : (r == 2) ? q1[2] : q1[3];
            float v = (j == 0) ? v0 : v1;
            int row = m0 + wv * 16 + quad * 4 + r;
            if (row < N) {
                int idx = nbr[(size_t)row * 27 + tap];
                if (idx < N)                    // guard: sentinel atomics serialize!
                    atomicAdd(&sout[(size_t)idx * 2 + j], v);
            }
        }
    }
}

// ===========================================================================
// Level 2 compute: persistent waves over compacted active-row list.
// Restructured (R6): 4-way acc split in the gather loop; score epilogue is
// transposed — lane l<54 owns output (tap=l>>1, j=l&1), its 48 score weights
// live in registers (row-invariant), acc[c] broadcast via v_readlane. One
// pass of 48 readlane+FMA per ROW replaces 27 shuffle-tree reductions.
// ===========================================================================
__global__ __launch_bounds__(256) void lvl2_compute(
    const float* __restrict__ feat2, const int* __restrict__ nbr2,
    const float* __restrict__ act, const float* __restrict__ W2,
    const float* __restrict__ W2s, float* __restrict__ s2,
    const int* __restrict__ list, const int* __restrict__ cnt, int N)
{
    const int lane = threadIdx.x & 63;
    const int wid0 = (blockIdx.x * 256 + threadIdx.x) >> 6;
    const int nw = (gridDim.x * 256) >> 6;
    const int count = *cnt;
    const int c = lane;
    const int cc48 = (c < 48) ? c : 0;          // safe weight column

    // Preload score weights: lane l owns (t=l>>1, j=l&1), l<54.
    // W2s layout [27][48][2]; we need W2s[26-t][cc][j] for cc=0..47.
    const int ot = lane >> 1, oj = lane & 1;
    const float* wsb = W2s + (size_t)((lane < 54) ? (26 - ot) : 0) * 96 + oj;
    float ws[48];
    #pragma unroll
    for (int q = 0; q < 48; ++q) ws[q] = wsb[q * 2];

    for (int w = wid0; w < count; w += nw) {
        const int n = list[w];
        int ld = N;
        if (lane < 27) ld = nbr2[(size_t)n * 27 + lane];
        float a = (lane < 27 && ld < N) ? act[ld] : 0.f;
        unsigned long long m = __ballot(a != 0.f);

        float a0 = 0.f, a1 = 0.f, a2 = 0.f, a3 = 0.f;
        while (m) {
            int t = __ffsll(m) - 1; m &= m - 1;
            int idx = __shfl(ld, t);
            const float4* f4 = (const float4*)(feat2 + (size_t)idx * 48);
            const float* wgt = W2 + (size_t)t * 48 * 48;
            #pragma unroll
            for (int q = 0; q < 12; ++q) {
                float4 fv = f4[q];                 // uniform address -> broadcast
                a0 += fv.x * wgt[(4 * q + 0) * 48 + cc48];
                a1 += fv.y * wgt[(4 * q + 1) * 48 + cc48];
                a2 += fv.z * wgt[(4 * q + 2) * 48 + cc48];
                a3 += fv.w * wgt[(4 * q + 3) * 48 + cc48];
            }
        }
        float acc = (a0 + a1) + (a2 + a3);         // y2[n][c] for c<48

        // transposed score epilogue: p(t,j) = sum_c acc[c] * ws[c]
        float p0 = 0.f, p1 = 0.f, p2 = 0.f, p3 = 0.f;
        #pragma unroll
        for (int q = 0; q < 48; q += 4) {
            p0 += bcast_lane(acc, q + 0) * ws[q + 0];
            p1 += bcast_lane(acc, q + 1) * ws[q + 1];
            p2 += bcast_lane(acc, q + 2) * ws[q + 2];
            p3 += bcast_lane(acc, q + 3) * ws[q + 3];
        }
        float p = (p0 + p1) + (p2 + p3);

        int idxt = __shfl(ld, ot);                 // neighbor index for my tap
        if (lane < 54 && idxt < N)
            atomicAdd(&s2[(size_t)idxt * 2 + oj], p);
    }
}

// ===========================================================================
// Level 3 compute kernels over compacted lists (zbuf / points pre-zeroed).
// ===========================================================================
__global__ __launch_bounds__(256) void lvl3_z_compute(
    const float* __restrict__ feat3, const int* __restrict__ nbr3,
    const float* __restrict__ act, const float* __restrict__ W3,
    float* __restrict__ z, const int* __restrict__ list,
    const int* __restrict__ cnt, int N)
{
    const int lane = threadIdx.x & 63;
    const int wid0 = (blockIdx.x * 256 + threadIdx.x) >> 6;
    const int nw = (gridDim.x * 256) >> 6;
    const int count = *cnt;
    const int c = lane;
    const int cc16 = (c < 16) ? c : 0;

    for (int w = wid0; w < count; w += nw) {
        const int n = list[w];
        int ld = N;
        if (lane < 27) ld = nbr3[(size_t)n * 27 + lane];
        bool valid = (lane < 27) && (ld < N);
        float a = valid ? act[ld] : 0.f;
        unsigned long long m = __ballot(a != 0.f);

        float a0 = 0.f, a1 = 0.f, a2 = 0.f, a3 = 0.f;
        while (m) {
            int t = __ffsll(m) - 1; m &= m - 1;
            int idx = __shfl(ld, t);
            const float4* f4 = (const float4*)(feat3 + (size_t)idx * 16);
            const float* wgt = W3 + (size_t)t * 256;
            #pragma unroll
            for (int q = 0; q < 4; ++q) {
                float4 fv = f4[q];
                a0 += fv.x * wgt[(4 * q + 0) * 16 + cc16];
                a1 += fv.y * wgt[(4 * q + 1) * 16 + cc16];
                a2 += fv.z * wgt[(4 * q + 2) * 16 + cc16];
                a3 += fv.w * wgt[(4 * q + 3) * 16 + cc16];
            }
        }
        if (lane < 16) z[(size_t)n * 16 + lane] = (a0 + a1) + (a2 + a3);
    }
}

__global__ __launch_bounds__(256) void lvl3_pts_compute(
    const float* __restrict__ z, const int* __restrict__ zflag,
    const int* __restrict__ nbr3,
    const float* __restrict__ Wp, const float* __restrict__ Ws,
    const float* __restrict__ Wt, float* __restrict__ points,
    const int* __restrict__ list, const int* __restrict__ cnt, int N)
{
    const int lane = threadIdx.x & 63;
    const int wid0 = (blockIdx.x * 256 + threadIdx.x) >> 6;
    const int nw = (gridDim.x * 256) >> 6;
    const int count = *cnt;
    const int c = (lane < 10) ? lane : 0;           // safe column

    for (int w = wid0; w < count; w += nw) {
        const int n = list[w];
        int ld = N;
        if (lane < 27) ld = nbr3[(size_t)n * 27 + lane];
        bool valid = (lane < 27) && (ld < N);
        int zf = valid ? zflag[ld] : 0;
        unsigned long long m = __ballot(zf != 0);

        float a0 = 0.f, a1 = 0.f, a2 = 0.f, a3 = 0.f;
        while (m) {
            int t = __ffsll(m) - 1; m &= m - 1;
            int idx = __shfl(ld, t);
            const float4* z4 = (const float4*)(z + (size_t)idx * 16);
            #pragma unroll
            for (int q = 0; q < 4; ++q) {
                float4 zv = z4[q];
                #pragma unroll
                for (int j = 0; j < 4; ++j) {
                    int k = 4 * q + j;
                    int kc = t * 16 + k;
                    float wv = (c < 3) ? Wp[(size_t)kc * 3 + c]
                             : (c < 5) ? Ws[(size_t)kc * 2 + (c - 3)]
                                       : Wt[(size_t)kc * 5 + (c - 5)];
                    float zj = (j == 0) ? zv.x : (j == 1) ? zv.y : (j == 2) ? zv.z : zv.w;
                    if (j == 0)      a0 += zj * wv;
                    else if (j == 1) a1 += zj * wv;
                    else if (j == 2) a2 += zj * wv;
                    else             a3 += zj * wv;
                }
            }
        }
        if (lane < 10) points[(size_t)n * 10 + lane] = (a0 + a1) + (a2 + a3);
    }
}

// ===========================================================================
extern "C" void kernel_launch(void* const* d_in, const int* in_sizes, int n_in,
                              void* d_out, int out_size, void* d_ws, size_t ws_size,
                              hipStream_t stream)
{
    const float* feat1 = (const float*)d_in[0];
    const float* feat2 = (const float*)d_in[1];
    const float* feat3 = (const float*)d_in[2];
    const float* W1    = (const float*)d_in[3];
    const float* W1s   = (const float*)d_in[4];
    const float* W2    = (const float*)d_in[5];
    const float* W2s   = (const float*)d_in[6];
    const float* W3    = (const float*)d_in[7];
    const float* W3p   = (const float*)d_in[8];
    const float* W3s   = (const float*)d_in[9];
    const float* W3t   = (const float*)d_in[10];
    const int* nbr1    = (const int*)d_in[11];
    const int* nbr2    = (const int*)d_in[12];
    const int* nbr3    = (const int*)d_in[13];
    const int* parent2 = (const int*)d_in[14];
    const int* parent3 = (const int*)d_in[15];
    const int* coords1 = (const int*)d_in[16];
    const int* coords2 = (const int*)d_in[17];

    const int N1 = in_sizes[0] / 80;
    const int N2 = in_sizes[1] / 48;
    const int N3 = in_sizes[2] / 16;

    float* out = (float*)d_out;
    float* o_points = out;                              // [N3,10]
    float* o_ppn1   = o_points + (size_t)N3 * 10;       // [N1,6]
    float* o_ppn2   = o_ppn1 + (size_t)N1 * 6;          // [N2,6]
    float* o_mask1  = o_ppn2 + (size_t)N2 * 6;          // [N1]
    float* o_mask2  = o_mask1 + (size_t)N1;             // [N2]

    char* wp = (char*)d_ws;
    auto alloc = [&](size_t bytes) -> char* {
        char* r = wp; wp += (bytes + 255) & ~(size_t)255; return r;
    };
    f16*   WT1   = (f16*)alloc((size_t)80 * 28 * 160 * 2);
    f16*   Fa    = (f16*)alloc((size_t)(N1 + 1) * 160 * 2);
    float* s1    = (float*)alloc((size_t)(N1 + 1) * 2 * 4);
    float* s2    = (float*)alloc((size_t)(N2 + 1) * 2 * 4);
    float* act2  = (float*)alloc((size_t)N2 * 4);
    float* act3  = (float*)alloc((size_t)N3 * 4);
    int*   flag2 = (int*)alloc((size_t)N2 * 4);
    int*   list2 = (int*)alloc((size_t)N2 * 4);
    int*   flagz = (int*)alloc((size_t)N3 * 4);
    int*   listz = (int*)alloc((size_t)N3 * 4);
    int*   flagp = (int*)alloc((size_t)N3 * 4);
    int*   listp = (int*)alloc((size_t)N3 * 4);
    float* zbuf  = (float*)alloc((size_t)N3 * 16 * 4);
    int*   cnts  = (int*)alloc(3 * 4);    // [cnt2, cntz, cntp]

    auto cdiv = [](long long a, long long b) { return (int)((a + b - 1) / b); };

    // zero the accumulators / flags / compacted counters / zero-default outputs
    hipMemsetAsync(s1, 0, (size_t)(N1 + 1) * 2 * 4, stream);
    hipMemsetAsync(s2, 0, (size_t)(N2 + 1) * 2 * 4, stream);
    hipMemsetAsync(flag2, 0, (size_t)N2 * 4, stream);
    hipMemsetAsync(flagz, 0, (size_t)N3 * 4, stream);
    hipMemsetAsync(flagp, 0, (size_t)N3 * 4, stream);
    hipMemsetAsync(zbuf, 0, (size_t)N3 * 16 * 4, stream);
    hipMemsetAsync(cnts, 0, 3 * 4, stream);
    hipMemsetAsync(o_points, 0, (size_t)N3 * 10 * 4, stream);

    // ---- level 1: dense MFMA conv80 + fused scatter score ----
    prep_w1_kernel<<<700, 256, 0, stream>>>(W1, WT1);
    split80_kernel<<<cdiv((size_t)(N1 + 1) * 80, 256), 256, 0, stream>>>(feat1, Fa, N1);
    {
        int T = cdiv(N1, 64);
        dim3 grid(8 * cdiv(T, 8));
        conv80_scat<<<grid, 256, 0, stream>>>(Fa, nbr1, WT1, W1s, s1, N1, T);
    }
    ppn_finalize_kernel<<<cdiv(N1, 256), 256, 0, stream>>>(coords1, s1, o_ppn1, o_mask1, N1);

    // ---- level 2: expand -> compact -> persistent sparse compute ----
    gate_kernel<<<cdiv(N2, 256), 256, 0, stream>>>(o_mask1, parent2, act2, N2);
    expand_kernel<true><<<cdiv(N2, 256), 256, 0, stream>>>(act2, nbr2, flag2, N2);
    compact_kernel<<<cdiv(N2, 256), 256, 0, stream>>>(flag2, list2, &cnts[0], N2);
    lvl2_compute<<<2048, 256, 0, stream>>>(feat2, nbr2, act2, W2, W2s, s2,
                                           list2, &cnts[0], N2);
    ppn_finalize_kernel<<<cdiv(N2, 256), 256, 0, stream>>>(coords2, s2, o_ppn2, o_mask2, N2);

    // ---- level 3: two-hop expand/compact, z then points ----
    gate_kernel<<<cdiv(N3, 256), 256, 0, stream>>>(o_mask2, parent3, act3, N3);
    expand_kernel<true><<<cdiv(N3, 256), 256, 0, stream>>>(act3, nbr3, flagz, N3);
    compact_kernel<<<cdiv(N3, 256), 256, 0, stream>>>(flagz, listz, &cnts[1], N3);
    lvl3_z_compute<<<2048, 256, 0, stream>>>(feat3, nbr3, act3, W3, zbuf,
                                             listz, &cnts[1], N3);
    expand_kernel<false><<<cdiv(N3, 256), 256, 0, stream>>>(flagz, nbr3, flagp, N3);
    compact_kernel<<<cdiv(N3, 256), 256, 0, stream>>>(flagp, listp, &cnts[2], N3);
    lvl3_pts_compute<<<2048, 256, 0, stream>>>(zbuf, flagz, nbr3, W3p, W3s, W3t,
                                               o_points, listp, &cnts[2], N3);
}